// Round 2
// 184.669 us; speedup vs baseline: 1.1334x; 1.1334x over previous
//
#include <hip/hip_runtime.h>
#include <stdint.h>

#pragma clang fp contract(off)

namespace {
constexpr int B_ = 2, V_ = 2, HC = 512, WC = 512, HF = 256, WF = 256, CF = 64;
constexpr int NPIX = HF * WF;                 // 65536
constexpr float EPSF = 1e-4f;
constexpr float BIGF = 1e10f;                 // exactly representable in f32
constexpr int NPT = B_ * V_ * NPIX;           // 262144
constexpr int NBLK_PT = NPT / 256;            // 1024 blocks per point-pass
// workspace layout: zwin (2 MiB) | colr (3 MiB) | mats (256 B) | tf (64 MiB, optional)
constexpr size_t WS_BASE = (size_t)NPT * 8 + (size_t)B_ * V_ * 3 * NPIX * 4 + 256;
constexpr size_t TF_BYTES = (size_t)NPT * CF * 4;
}

// NON-FMA ascending f32 dot4 (fp contract off TU-wide keeps mul/add separate).
__device__ __forceinline__ float dot4f(const float* __restrict__ r,
                                       float v0, float v1, float v2, float v3) {
  float t = r[0] * v0;
  t = t + r[1] * v1;
  t = t + r[2] * v2;
  t = t + r[3] * v3;
  return t;
}

// --- fused prep: zwin init + per-batch matrices + antialiased color resize ---
// grid: 3072 blocks x 256 (one thread per resize output element = 786432).
__global__ void prep_k(const float* __restrict__ K,
                       const float* __restrict__ colors,
                       float* __restrict__ colr,
                       float* __restrict__ mats,
                       unsigned long long* __restrict__ zwin) {
  int g = blockIdx.x * blockDim.x + threadIdx.x;

  if (g < NPT) zwin[g] = ~0ULL;

  if (g < B_) {                      // per-batch sK / sKinv (f64 adjugate -> f32)
    int b = g;
    const float rowscale[4] = {0.5f, 0.5f, 1.0f, 1.0f};
    float sK[16];
    for (int i = 0; i < 4; ++i)
      for (int j = 0; j < 4; ++j)
        sK[i*4+j] = K[b*16 + i*4 + j] * rowscale[i];
    double m[16];
    for (int i = 0; i < 16; ++i) m[i] = (double)sK[i];
    double inv[16];
    inv[0]  =  m[5]*m[10]*m[15] - m[5]*m[11]*m[14] - m[9]*m[6]*m[15] + m[9]*m[7]*m[14] + m[13]*m[6]*m[11] - m[13]*m[7]*m[10];
    inv[4]  = -m[4]*m[10]*m[15] + m[4]*m[11]*m[14] + m[8]*m[6]*m[15] - m[8]*m[7]*m[14] - m[12]*m[6]*m[11] + m[12]*m[7]*m[10];
    inv[8]  =  m[4]*m[9]*m[15]  - m[4]*m[11]*m[13] - m[8]*m[5]*m[15] + m[8]*m[7]*m[13] + m[12]*m[5]*m[11] - m[12]*m[7]*m[9];
    inv[12] = -m[4]*m[9]*m[14]  + m[4]*m[10]*m[13] + m[8]*m[5]*m[14] - m[8]*m[6]*m[13] - m[12]*m[5]*m[10] + m[12]*m[6]*m[9];
    inv[1]  = -m[1]*m[10]*m[15] + m[1]*m[11]*m[14] + m[9]*m[2]*m[15] - m[9]*m[3]*m[14] - m[13]*m[2]*m[11] + m[13]*m[3]*m[10];
    inv[5]  =  m[0]*m[10]*m[15] - m[0]*m[11]*m[14] - m[8]*m[2]*m[15] + m[8]*m[3]*m[14] + m[12]*m[2]*m[11] - m[12]*m[3]*m[10];
    inv[9]  = -m[0]*m[9]*m[15]  + m[0]*m[11]*m[13] + m[8]*m[1]*m[15] - m[8]*m[3]*m[13] - m[12]*m[1]*m[11] + m[12]*m[3]*m[9];
    inv[13] =  m[0]*m[9]*m[14]  - m[0]*m[10]*m[13] - m[8]*m[1]*m[14] + m[8]*m[2]*m[13] + m[12]*m[1]*m[10] - m[12]*m[2]*m[9];
    inv[2]  =  m[1]*m[6]*m[15]  - m[1]*m[7]*m[14]  - m[5]*m[2]*m[15] + m[5]*m[3]*m[14] + m[13]*m[2]*m[7]  - m[13]*m[3]*m[6];
    inv[6]  = -m[0]*m[6]*m[15]  + m[0]*m[7]*m[14]  + m[4]*m[2]*m[15] - m[4]*m[3]*m[14] - m[12]*m[2]*m[7]  + m[12]*m[3]*m[6];
    inv[10] =  m[0]*m[5]*m[15]  - m[0]*m[7]*m[13]  - m[4]*m[1]*m[15] + m[4]*m[3]*m[13] + m[12]*m[1]*m[7]  - m[12]*m[3]*m[5];
    inv[14] = -m[0]*m[5]*m[14]  + m[0]*m[6]*m[13]  + m[4]*m[1]*m[14] - m[4]*m[2]*m[13] - m[12]*m[1]*m[6]  + m[12]*m[2]*m[5];
    inv[3]  = -m[1]*m[6]*m[11]  + m[1]*m[7]*m[10]  + m[5]*m[2]*m[11] - m[5]*m[3]*m[10] - m[9]*m[2]*m[7]   + m[9]*m[3]*m[6];
    inv[7]  =  m[0]*m[6]*m[11]  - m[0]*m[7]*m[10]  - m[4]*m[2]*m[11] + m[4]*m[3]*m[10] + m[8]*m[2]*m[7]   - m[8]*m[3]*m[6];
    inv[11] = -m[0]*m[5]*m[11]  + m[0]*m[7]*m[9]   + m[4]*m[1]*m[11] - m[4]*m[3]*m[9]  - m[8]*m[1]*m[7]   + m[8]*m[3]*m[5];
    inv[15] =  m[0]*m[5]*m[10]  - m[0]*m[6]*m[9]   - m[4]*m[1]*m[10] + m[4]*m[2]*m[9]  + m[8]*m[1]*m[6]   - m[8]*m[2]*m[5];
    double det = m[0]*inv[0] + m[1]*inv[4] + m[2]*inv[8] + m[3]*inv[12];
    double idet = 1.0 / det;
    for (int i = 0; i < 16; ++i) {
      mats[b*32 + i]      = sK[i];
      mats[b*32 + 16 + i] = (float)(inv[i] * idet);
    }
  }

  // antialiased linear 2x downsample of colors (same arithmetic as r5)
  if (g >= B_ * V_ * 3 * NPIX) return;
  int pc  = g >> 16;            // bv*3 + ch
  int pix = g & (NPIX - 1);
  int y = pix >> 8, x = pix & (WF - 1);
  const float* src = colors + (size_t)pc * HC * WC;
  const float W37 = (float)(3.0 / 7.0), W17 = (float)(1.0 / 7.0);
  float wy[4] = {0.125f, 0.375f, 0.375f, 0.125f};
  float wx[4] = {0.125f, 0.375f, 0.375f, 0.125f};
  if (y == 0)      { wy[0] = 0.f; wy[1] = W37; wy[2] = W37; wy[3] = W17; }
  if (y == HF - 1) { wy[0] = W17; wy[1] = W37; wy[2] = W37; wy[3] = 0.f; }
  if (x == 0)      { wx[0] = 0.f; wx[1] = W37; wx[2] = W37; wx[3] = W17; }
  if (x == WF - 1) { wx[0] = W17; wx[1] = W37; wx[2] = W37; wx[3] = 0.f; }
  int jy0 = 2 * y - 1, jx0 = 2 * x - 1;
  float acc = 0.f;
  #pragma unroll
  for (int ty = 0; ty < 4; ++ty) {
    if (wy[ty] == 0.f) continue;       // also guards OOB rows
    int jy = jy0 + ty;
    float rs = 0.f;
    #pragma unroll
    for (int tx = 0; tx < 4; ++tx) {
      if (wx[tx] == 0.f) continue;     // also guards OOB cols
      rs = rs + wx[tx] * src[(size_t)jy * WC + (jx0 + tx)];
    }
    acc = acc + wy[ty] * rs;
  }
  colr[g] = acc;
}

// --- feats transpose (bv,c,pix) -> (bv,pix,c): makes the gather read one
// aligned, fully-consumed 256B chunk per winner instead of 64 scattered 4B
// reads across channel planes (measured 2.4x fetch amplification).
// grid: 4096 blocks x 256; tile = 64 ch x 64 pix; LDS 64x65 (2-way alias = free).
__global__ void transp_k(const float* __restrict__ feats,
                         float* __restrict__ tf) {
  __shared__ float lds[CF][65];
  int bid = blockIdx.x;
  int bv = bid >> 10;                  // NPIX/64 = 1024 tiles per bv
  int pix0 = (bid & 1023) << 6;
  int t = threadIdx.x;
  int sub = t >> 4;                    // 0..15
  int l16 = t & 15;                    // 0..15
  const float* fb = feats + (size_t)bv * CF * NPIX;
  #pragma unroll
  for (int pass = 0; pass < 4; ++pass) {
    int ch = pass * 16 + sub;
    const float4 v = *(const float4*)(fb + (size_t)ch * NPIX + pix0 + 4 * l16);
    lds[ch][4*l16+0] = v.x; lds[ch][4*l16+1] = v.y;
    lds[ch][4*l16+2] = v.z; lds[ch][4*l16+3] = v.w;
  }
  __syncthreads();
  float* tb = tf + ((size_t)bv * NPIX + pix0) * CF;
  #pragma unroll
  for (int pass = 0; pass < 4; ++pass) {
    int p = pass * 16 + sub;
    float4 w;
    w.x = lds[4*l16+0][p]; w.y = lds[4*l16+1][p];
    w.z = lds[4*l16+2][p]; w.w = lds[4*l16+3][p];
    *(float4*)(tb + (size_t)p * CF + 4 * l16) = w;   // plain stores (A/B vs nt)
  }
}

// --- f32 projection + single-pass z-buffer via packed (z_bits<<32 | idx) ---
// Numerics byte-identical to the r5 PASSING kernel. Do not touch.
__global__ void splat_k(const float* __restrict__ depths,
                        const float* __restrict__ mats,
                        const float* __restrict__ srcRTinv,
                        const float* __restrict__ dstRT,
                        unsigned long long* __restrict__ zwin) {
  int g = blockIdx.x * blockDim.x + threadIdx.x;
  if (g >= NPT) return;
  int bv = g >> 16;
  int n  = g & (NPIX - 1);
  int b  = bv / V_;
  int y = n >> 8, x = n & (WF - 1);
  // nearest resize 512->256 picks input index floor((i+0.5)*2) = 2i+1
  float d = depths[(size_t)bv * HC * WC + (size_t)(2 * y + 1) * WC + (2 * x + 1)];
  // jax-native f32 linspace(-1,1,256): step32 = fl32(2/255);
  // x_i = fl32(fl32(i*step32) - 1); 255*step32 rounds to exactly 2.0 -> x_255=1.
  const float step32 = 2.0f / 255.0f;
  float xf = (float)x * step32 - 1.0f;
  float yf = (float)y * step32 - 1.0f;
  float pr0 = xf * d, pr1 = yf * d, pr2 = d, pr3 = 1.0f;
  const float* sK  = mats + b * 32;
  const float* sKi = mats + b * 32 + 16;
  const float* Rs  = srcRTinv + (size_t)bv * 16;
  const float* Rd  = dstRT + (size_t)b * 16;     // dst_RTs[:,0]
  float a0 = dot4f(sKi + 0,  pr0, pr1, pr2, pr3);
  float a1 = dot4f(sKi + 4,  pr0, pr1, pr2, pr3);
  float a2 = dot4f(sKi + 8,  pr0, pr1, pr2, pr3);
  float a3 = dot4f(sKi + 12, pr0, pr1, pr2, pr3);
  float w0 = dot4f(Rs + 0,  a0, a1, a2, a3);
  float w1 = dot4f(Rs + 4,  a0, a1, a2, a3);
  float w2 = dot4f(Rs + 8,  a0, a1, a2, a3);
  float w3 = dot4f(Rs + 12, a0, a1, a2, a3);
  float c0 = dot4f(Rd + 0,  w0, w1, w2, w3);
  float c1 = dot4f(Rd + 4,  w0, w1, w2, w3);
  float c2 = dot4f(Rd + 8,  w0, w1, w2, w3);
  float c3 = dot4f(Rd + 12, w0, w1, w2, w3);
  float p0 = dot4f(sK + 0, c0, c1, c2, c3);
  float p1 = dot4f(sK + 4, c0, c1, c2, c3);
  float p2 = dot4f(sK + 8, c0, c1, c2, c3);
  if (!(p2 > EPSF)) return;
  float sx = p0 / p2, sy = p1 / p2;                 // f32 IEEE division
  float pxf = rintf(((sx + 1.0f) * 0.5f) * 255.0f); // jnp.round = half-to-even
  float pyf = rintf(((sy + 1.0f) * 0.5f) * 255.0f);
  if (!(pxf >= 0.0f && pxf <= 255.0f && pyf >= 0.0f && pyf <= 255.0f)) return;
  int idx = (int)pyf * WF + (int)pxf;
  unsigned zbits = __float_as_uint(p2);             // p2>0 -> order-preserving bits
  unsigned long long key = ((unsigned long long)zbits << 32) | (unsigned)n;
  atomicMin(&zwin[(size_t)bv * NPIX + idx], key);
}

// --- gather from transposed feats: one thread per dst pixel does all 64 feat
// channels (4 aligned float4 loads = 4 fully-used lines) + colors + depth.
// zwin read once (was 5x). grid = NBLK_PT x 256.
__global__ void gatherT_k(const unsigned long long* __restrict__ zwin,
                          const float* __restrict__ tf,
                          const float* __restrict__ colr,
                          float* __restrict__ out0,
                          float* __restrict__ out1,
                          float* __restrict__ out2) {
  int g = blockIdx.x * 256 + threadIdx.x;
  int bv = g >> 16;
  int pix = g & (NPIX - 1);
  unsigned long long key = zwin[g];
  bool hit = (key != ~0ULL);
  int n = (int)(key & 0xffffffffULL);
  float4 f[16];
  if (hit) {
    const float4* src = (const float4*)(tf + ((size_t)bv * NPIX + n) * CF);
    #pragma unroll
    for (int i = 0; i < 16; ++i) f[i] = src[i];
  } else {
    #pragma unroll
    for (int i = 0; i < 16; ++i) f[i] = make_float4(0.f, 0.f, 0.f, 0.f);
  }
  float* o0 = out0 + (size_t)bv * CF * NPIX + pix;
  const float* fs = (const float*)f;
  #pragma unroll
  for (int c = 0; c < CF; ++c)
    __builtin_nontemporal_store(fs[c], &o0[(size_t)c * NPIX]);

  int b = bv >> 1, v = bv & 1;         // V_ == 2
  const float* cb = colr + (size_t)bv * 3 * NPIX;
  float* o1 = out1 + (size_t)(v * B_ + b) * 3 * NPIX + pix;
  if (hit) {
    float z = __uint_as_float((unsigned)(key >> 32));
    __builtin_nontemporal_store((z < BIGF) ? z : 0.0f, &out2[g]);
    #pragma unroll
    for (int ch = 0; ch < 3; ++ch)
      __builtin_nontemporal_store(cb[(size_t)ch * NPIX + n] * 0.5f + 0.5f,
                                  &o1[(size_t)ch * NPIX]);
  } else {
    __builtin_nontemporal_store(0.0f, &out2[g]);
    #pragma unroll
    for (int ch = 0; ch < 3; ++ch)
      __builtin_nontemporal_store(0.0f, &o1[(size_t)ch * NPIX]);
  }
}

// --- fallback gather (exact previous passing kernel) used if ws too small ---
__global__ void gather_k(const unsigned long long* __restrict__ zwin,
                         const float* __restrict__ feats,
                         const float* __restrict__ colr,
                         float* __restrict__ out0,
                         float* __restrict__ out1,
                         float* __restrict__ out2) {
  int bid = blockIdx.x;
  int grp = bid >> 10;                 // /NBLK_PT
  int g   = (bid & (NBLK_PT - 1)) * 256 + threadIdx.x;   // point id
  int bv  = g >> 16;
  int pix = g & (NPIX - 1);
  unsigned long long key = zwin[g];
  bool hit = (key != ~0ULL);
  int n = (int)(key & 0xffffffffULL);

  if (grp < 4) {                       // 16 feat channels
    int c0 = grp * 16;
    const float* fb = feats + (size_t)bv * CF * NPIX + (size_t)c0 * NPIX;
    float* o0 = out0 + (size_t)bv * CF * NPIX + (size_t)c0 * NPIX + pix;
    if (hit) {
      #pragma unroll
      for (int c = 0; c < 16; ++c)
        __builtin_nontemporal_store(fb[(size_t)c * NPIX + n], &o0[(size_t)c * NPIX]);
    } else {
      #pragma unroll
      for (int c = 0; c < 16; ++c)
        __builtin_nontemporal_store(0.0f, &o0[(size_t)c * NPIX]);
    }
  } else {                             // colors (V,B,3,H,W layout!) + depth
    int b = bv >> 1, v = bv & 1;       // V_ == 2
    const float* cb = colr + (size_t)bv * 3 * NPIX;
    float* o1 = out1 + (size_t)(v * B_ + b) * 3 * NPIX + pix;
    if (hit) {
      float z = __uint_as_float((unsigned)(key >> 32));
      __builtin_nontemporal_store((z < BIGF) ? z : 0.0f, &out2[g]);
      #pragma unroll
      for (int ch = 0; ch < 3; ++ch)
        __builtin_nontemporal_store(cb[(size_t)ch * NPIX + n] * 0.5f + 0.5f,
                                    &o1[(size_t)ch * NPIX]);
    } else {
      __builtin_nontemporal_store(0.0f, &out2[g]);
      #pragma unroll
      for (int ch = 0; ch < 3; ++ch)
        __builtin_nontemporal_store(0.0f, &o1[(size_t)ch * NPIX]);
    }
  }
}

extern "C" void kernel_launch(void* const* d_in, const int* in_sizes, int n_in,
                              void* d_out, int out_size, void* d_ws, size_t ws_size,
                              hipStream_t stream) {
  const float* depths     = (const float*)d_in[0];
  const float* colors     = (const float*)d_in[1];
  const float* feats      = (const float*)d_in[2];
  const float* K          = (const float*)d_in[3];
  const float* src_RTinvs = (const float*)d_in[5];
  const float* dst_RTs    = (const float*)d_in[6];

  float* out0 = (float*)d_out;                                  // (B,V,64,256,256)
  float* out1 = out0 + (size_t)B_ * V_ * CF * NPIX;             // (V,B,3,256,256)
  float* out2 = out1 + (size_t)V_ * B_ * 3 * NPIX;              // (B,V,1,256,256)

  unsigned long long* zwin = (unsigned long long*)d_ws;         // 2 MiB
  float* colr = (float*)(zwin + NPT);                           // 3 MiB
  float* mats = colr + (size_t)B_ * V_ * 3 * NPIX;              // 256 B
  float* tf   = (float*)((char*)d_ws + WS_BASE);                // 64 MiB (16B-aligned)

  const bool use_tf = (ws_size >= WS_BASE + TF_BYTES);

  prep_k<<<(B_ * V_ * 3 * NPIX) / 256, 256, 0, stream>>>(K, colors, colr, mats, zwin);
  if (use_tf)
    transp_k<<<B_ * V_ * (NPIX / 64), 256, 0, stream>>>(feats, tf);
  splat_k<<<NBLK_PT, 256, 0, stream>>>(depths, mats, src_RTinvs, dst_RTs, zwin);
  if (use_tf)
    gatherT_k<<<NBLK_PT, 256, 0, stream>>>(zwin, tf, colr, out0, out1, out2);
  else
    gather_k<<<5 * NBLK_PT, 256, 0, stream>>>(zwin, feats, colr, out0, out1, out2);
}

// Round 3
// 180.455 us; speedup vs baseline: 1.1599x; 1.0234x over previous
//
#include <hip/hip_runtime.h>
#include <stdint.h>

#pragma clang fp contract(off)

namespace {
constexpr int B_ = 2, V_ = 2, HC = 512, WC = 512, HF = 256, WF = 256, CF = 64;
constexpr int NPIX = HF * WF;                 // 65536
constexpr float EPSF = 1e-4f;
constexpr float BIGF = 1e10f;                 // exactly representable in f32
constexpr int NPT = B_ * V_ * NPIX;           // 262144
constexpr int NBLK_PT = NPT / 256;            // 1024 blocks per point-pass
constexpr int RESIZE_BLKS = (B_ * V_ * 3 * NPIX) / 256;   // 3072
constexpr int TRANSP_BLKS = B_ * V_ * (NPIX / 64);        // 4096
// workspace layout: zwin (2 MiB) | colr (3 MiB) | mats (256 B) | tf (64 MiB, optional)
constexpr size_t WS_BASE = (size_t)NPT * 8 + (size_t)B_ * V_ * 3 * NPIX * 4 + 256;
constexpr size_t TF_BYTES = (size_t)NPT * CF * 4;
}

// NON-FMA ascending f32 dot4 (fp contract off TU-wide keeps mul/add separate).
__device__ __forceinline__ float dot4f(const float* __restrict__ r,
                                       float v0, float v1, float v2, float v3) {
  float t = r[0] * v0;
  t = t + r[1] * v1;
  t = t + r[2] * v2;
  t = t + r[3] * v3;
  return t;
}

// --- fused prep: feats transpose + zwin init + per-batch matrices + color resize.
// Blocks [0, nT): transpose (bv,c,pix) -> (bv,pix,c), 64ch x 64pix tiles via LDS.
// Blocks [nT, nT+3072): antialiased 2x color downsample + zwin init + mats.
// When launched with grid == 3072 (no-tf fallback), nT == 0 and only resize runs.
__global__ void prep_k(const float* __restrict__ K,
                       const float* __restrict__ colors,
                       const float* __restrict__ feats,
                       float* __restrict__ colr,
                       float* __restrict__ mats,
                       unsigned long long* __restrict__ zwin,
                       float* __restrict__ tf) {
  __shared__ float lds[CF][65];
  int bid = blockIdx.x;
  int nT = (int)gridDim.x - RESIZE_BLKS;
  int t = threadIdx.x;

  if (bid < nT) {                      // ---- transpose tile ----
    int bv = bid >> 10;                // NPIX/64 = 1024 tiles per bv
    int pix0 = (bid & 1023) << 6;
    int sub = t >> 4;                  // 0..15
    int l16 = t & 15;                  // 0..15
    const float* fb = feats + (size_t)bv * CF * NPIX;
    #pragma unroll
    for (int pass = 0; pass < 4; ++pass) {
      int ch = pass * 16 + sub;
      const float4 v = *(const float4*)(fb + (size_t)ch * NPIX + pix0 + 4 * l16);
      lds[ch][4*l16+0] = v.x; lds[ch][4*l16+1] = v.y;
      lds[ch][4*l16+2] = v.z; lds[ch][4*l16+3] = v.w;
    }
    __syncthreads();
    float* tb = tf + ((size_t)bv * NPIX + pix0) * CF;
    #pragma unroll
    for (int pass = 0; pass < 4; ++pass) {
      int p = pass * 16 + sub;
      float4 w;
      w.x = lds[4*l16+0][p]; w.y = lds[4*l16+1][p];
      w.z = lds[4*l16+2][p]; w.w = lds[4*l16+3][p];
      *(float4*)(tb + (size_t)p * CF + 4 * l16) = w;
    }
    return;
  }

  int g = (bid - nT) * 256 + t;

  if (g < NPT) zwin[g] = ~0ULL;

  if (g < B_) {                      // per-batch sK / sKinv (f64 adjugate -> f32)
    int b = g;
    const float rowscale[4] = {0.5f, 0.5f, 1.0f, 1.0f};
    float sK[16];
    for (int i = 0; i < 4; ++i)
      for (int j = 0; j < 4; ++j)
        sK[i*4+j] = K[b*16 + i*4 + j] * rowscale[i];
    double m[16];
    for (int i = 0; i < 16; ++i) m[i] = (double)sK[i];
    double inv[16];
    inv[0]  =  m[5]*m[10]*m[15] - m[5]*m[11]*m[14] - m[9]*m[6]*m[15] + m[9]*m[7]*m[14] + m[13]*m[6]*m[11] - m[13]*m[7]*m[10];
    inv[4]  = -m[4]*m[10]*m[15] + m[4]*m[11]*m[14] + m[8]*m[6]*m[15] - m[8]*m[7]*m[14] - m[12]*m[6]*m[11] + m[12]*m[7]*m[10];
    inv[8]  =  m[4]*m[9]*m[15]  - m[4]*m[11]*m[13] - m[8]*m[5]*m[15] + m[8]*m[7]*m[13] + m[12]*m[5]*m[11] - m[12]*m[7]*m[9];
    inv[12] = -m[4]*m[9]*m[14]  + m[4]*m[10]*m[13] + m[8]*m[5]*m[14] - m[8]*m[6]*m[13] - m[12]*m[5]*m[10] + m[12]*m[6]*m[9];
    inv[1]  = -m[1]*m[10]*m[15] + m[1]*m[11]*m[14] + m[9]*m[2]*m[15] - m[9]*m[3]*m[14] - m[13]*m[2]*m[11] + m[13]*m[3]*m[10];
    inv[5]  =  m[0]*m[10]*m[15] - m[0]*m[11]*m[14] - m[8]*m[2]*m[15] + m[8]*m[3]*m[14] + m[12]*m[2]*m[11] - m[12]*m[3]*m[10];
    inv[9]  = -m[0]*m[9]*m[15]  + m[0]*m[11]*m[13] + m[8]*m[1]*m[15] - m[8]*m[3]*m[13] - m[12]*m[1]*m[11] + m[12]*m[3]*m[9];
    inv[13] =  m[0]*m[9]*m[14]  - m[0]*m[10]*m[13] - m[8]*m[1]*m[14] + m[8]*m[2]*m[13] + m[12]*m[1]*m[10] - m[12]*m[2]*m[9];
    inv[2]  =  m[1]*m[6]*m[15]  - m[1]*m[7]*m[14]  - m[5]*m[2]*m[15] + m[5]*m[3]*m[14] + m[13]*m[2]*m[7]  - m[13]*m[3]*m[6];
    inv[6]  = -m[0]*m[6]*m[15]  + m[0]*m[7]*m[14]  + m[4]*m[2]*m[15] - m[4]*m[3]*m[14] - m[12]*m[2]*m[7]  + m[12]*m[3]*m[6];
    inv[10] =  m[0]*m[5]*m[15]  - m[0]*m[7]*m[13]  - m[4]*m[1]*m[15] + m[4]*m[3]*m[13] + m[12]*m[1]*m[7]  - m[12]*m[3]*m[5];
    inv[14] = -m[0]*m[5]*m[14]  + m[0]*m[6]*m[13]  + m[4]*m[1]*m[14] - m[4]*m[2]*m[13] - m[12]*m[1]*m[6]  + m[12]*m[2]*m[5];
    inv[3]  = -m[1]*m[6]*m[11]  + m[1]*m[7]*m[10]  + m[5]*m[2]*m[11] - m[5]*m[3]*m[10] - m[9]*m[2]*m[7]   + m[9]*m[3]*m[6];
    inv[7]  =  m[0]*m[6]*m[11]  - m[0]*m[7]*m[10]  - m[4]*m[2]*m[11] + m[4]*m[3]*m[10] + m[8]*m[2]*m[7]   - m[8]*m[3]*m[6];
    inv[11] = -m[0]*m[5]*m[11]  + m[0]*m[7]*m[9]   + m[4]*m[1]*m[11] - m[4]*m[3]*m[9]  - m[8]*m[1]*m[7]   + m[8]*m[3]*m[5];
    inv[15] =  m[0]*m[5]*m[10]  - m[0]*m[6]*m[9]   - m[4]*m[1]*m[10] + m[4]*m[2]*m[9]  + m[8]*m[1]*m[6]   - m[8]*m[2]*m[5];
    double det = m[0]*inv[0] + m[1]*inv[4] + m[2]*inv[8] + m[3]*inv[12];
    double idet = 1.0 / det;
    for (int i = 0; i < 16; ++i) {
      mats[b*32 + i]      = sK[i];
      mats[b*32 + 16 + i] = (float)(inv[i] * idet);
    }
  }

  // antialiased linear 2x downsample of colors (same arithmetic as r5)
  int pc  = g >> 16;            // bv*3 + ch
  int pix = g & (NPIX - 1);
  int y = pix >> 8, x = pix & (WF - 1);
  const float* src = colors + (size_t)pc * HC * WC;
  const float W37 = (float)(3.0 / 7.0), W17 = (float)(1.0 / 7.0);
  float wy[4] = {0.125f, 0.375f, 0.375f, 0.125f};
  float wx[4] = {0.125f, 0.375f, 0.375f, 0.125f};
  if (y == 0)      { wy[0] = 0.f; wy[1] = W37; wy[2] = W37; wy[3] = W17; }
  if (y == HF - 1) { wy[0] = W17; wy[1] = W37; wy[2] = W37; wy[3] = 0.f; }
  if (x == 0)      { wx[0] = 0.f; wx[1] = W37; wx[2] = W37; wx[3] = W17; }
  if (x == WF - 1) { wx[0] = W17; wx[1] = W37; wx[2] = W37; wx[3] = 0.f; }
  int jy0 = 2 * y - 1, jx0 = 2 * x - 1;
  float acc = 0.f;
  #pragma unroll
  for (int ty = 0; ty < 4; ++ty) {
    if (wy[ty] == 0.f) continue;       // also guards OOB rows
    int jy = jy0 + ty;
    float rs = 0.f;
    #pragma unroll
    for (int tx = 0; tx < 4; ++tx) {
      if (wx[tx] == 0.f) continue;     // also guards OOB cols
      rs = rs + wx[tx] * src[(size_t)jy * WC + (jx0 + tx)];
    }
    acc = acc + wy[ty] * rs;
  }
  colr[g] = acc;
}

// --- f32 projection + single-pass z-buffer via packed (z_bits<<32 | idx) ---
// Numerics byte-identical to the r5 PASSING kernel. Do not touch.
__global__ void splat_k(const float* __restrict__ depths,
                        const float* __restrict__ mats,
                        const float* __restrict__ srcRTinv,
                        const float* __restrict__ dstRT,
                        unsigned long long* __restrict__ zwin) {
  int g = blockIdx.x * blockDim.x + threadIdx.x;
  if (g >= NPT) return;
  int bv = g >> 16;
  int n  = g & (NPIX - 1);
  int b  = bv / V_;
  int y = n >> 8, x = n & (WF - 1);
  // nearest resize 512->256 picks input index floor((i+0.5)*2) = 2i+1
  float d = depths[(size_t)bv * HC * WC + (size_t)(2 * y + 1) * WC + (2 * x + 1)];
  // jax-native f32 linspace(-1,1,256): step32 = fl32(2/255);
  // x_i = fl32(fl32(i*step32) - 1); 255*step32 rounds to exactly 2.0 -> x_255=1.
  const float step32 = 2.0f / 255.0f;
  float xf = (float)x * step32 - 1.0f;
  float yf = (float)y * step32 - 1.0f;
  float pr0 = xf * d, pr1 = yf * d, pr2 = d, pr3 = 1.0f;
  const float* sK  = mats + b * 32;
  const float* sKi = mats + b * 32 + 16;
  const float* Rs  = srcRTinv + (size_t)bv * 16;
  const float* Rd  = dstRT + (size_t)b * 16;     // dst_RTs[:,0]
  float a0 = dot4f(sKi + 0,  pr0, pr1, pr2, pr3);
  float a1 = dot4f(sKi + 4,  pr0, pr1, pr2, pr3);
  float a2 = dot4f(sKi + 8,  pr0, pr1, pr2, pr3);
  float a3 = dot4f(sKi + 12, pr0, pr1, pr2, pr3);
  float w0 = dot4f(Rs + 0,  a0, a1, a2, a3);
  float w1 = dot4f(Rs + 4,  a0, a1, a2, a3);
  float w2 = dot4f(Rs + 8,  a0, a1, a2, a3);
  float w3 = dot4f(Rs + 12, a0, a1, a2, a3);
  float c0 = dot4f(Rd + 0,  w0, w1, w2, w3);
  float c1 = dot4f(Rd + 4,  w0, w1, w2, w3);
  float c2 = dot4f(Rd + 8,  w0, w1, w2, w3);
  float c3 = dot4f(Rd + 12, w0, w1, w2, w3);
  float p0 = dot4f(sK + 0, c0, c1, c2, c3);
  float p1 = dot4f(sK + 4, c0, c1, c2, c3);
  float p2 = dot4f(sK + 8, c0, c1, c2, c3);
  if (!(p2 > EPSF)) return;
  float sx = p0 / p2, sy = p1 / p2;                 // f32 IEEE division
  float pxf = rintf(((sx + 1.0f) * 0.5f) * 255.0f); // jnp.round = half-to-even
  float pyf = rintf(((sy + 1.0f) * 0.5f) * 255.0f);
  if (!(pxf >= 0.0f && pxf <= 255.0f && pyf >= 0.0f && pyf <= 255.0f)) return;
  int idx = (int)pyf * WF + (int)pxf;
  unsigned zbits = __float_as_uint(p2);             // p2>0 -> order-preserving bits
  unsigned long long key = ((unsigned long long)zbits << 32) | (unsigned)n;
  atomicMin(&zwin[(size_t)bv * NPIX + idx], key);
}

// --- gather from transposed feats, 5 block-groups for occupancy (74% regime):
// grp 0..3: 16 feat channels = one fully-used 64B line of the winner's record.
// grp 4:    colors (V,B,3,H,W layout!) + depth.
// grid = 5 * NBLK_PT blocks x 256.
__global__ void gatherT_k(const unsigned long long* __restrict__ zwin,
                          const float* __restrict__ tf,
                          const float* __restrict__ colr,
                          float* __restrict__ out0,
                          float* __restrict__ out1,
                          float* __restrict__ out2) {
  int bid = blockIdx.x;
  int grp = bid >> 10;                 // /NBLK_PT
  int g   = (bid & (NBLK_PT - 1)) * 256 + threadIdx.x;   // point id
  int bv  = g >> 16;
  int pix = g & (NPIX - 1);
  unsigned long long key = zwin[g];
  bool hit = (key != ~0ULL);
  int n = (int)(key & 0xffffffffULL);

  if (grp < 4) {                       // 16 feat channels = 4 float4 = 64B line
    float4 f[4];
    if (hit) {
      const float4* src =
          (const float4*)(tf + ((size_t)bv * NPIX + n) * CF + grp * 16);
      #pragma unroll
      for (int i = 0; i < 4; ++i) f[i] = src[i];
    } else {
      #pragma unroll
      for (int i = 0; i < 4; ++i) f[i] = make_float4(0.f, 0.f, 0.f, 0.f);
    }
    float* o0 = out0 + (size_t)bv * CF * NPIX + (size_t)(grp * 16) * NPIX + pix;
    const float* fs = (const float*)f;
    #pragma unroll
    for (int c = 0; c < 16; ++c)
      __builtin_nontemporal_store(fs[c], &o0[(size_t)c * NPIX]);
  } else {                             // colors + depth
    int b = bv >> 1, v = bv & 1;       // V_ == 2
    const float* cb = colr + (size_t)bv * 3 * NPIX;
    float* o1 = out1 + (size_t)(v * B_ + b) * 3 * NPIX + pix;
    if (hit) {
      float z = __uint_as_float((unsigned)(key >> 32));
      __builtin_nontemporal_store((z < BIGF) ? z : 0.0f, &out2[g]);
      #pragma unroll
      for (int ch = 0; ch < 3; ++ch)
        __builtin_nontemporal_store(cb[(size_t)ch * NPIX + n] * 0.5f + 0.5f,
                                    &o1[(size_t)ch * NPIX]);
    } else {
      __builtin_nontemporal_store(0.0f, &out2[g]);
      #pragma unroll
      for (int ch = 0; ch < 3; ++ch)
        __builtin_nontemporal_store(0.0f, &o1[(size_t)ch * NPIX]);
    }
  }
}

// --- fallback gather (exact r0 passing kernel) used if ws too small ---
__global__ void gather_k(const unsigned long long* __restrict__ zwin,
                         const float* __restrict__ feats,
                         const float* __restrict__ colr,
                         float* __restrict__ out0,
                         float* __restrict__ out1,
                         float* __restrict__ out2) {
  int bid = blockIdx.x;
  int grp = bid >> 10;                 // /NBLK_PT
  int g   = (bid & (NBLK_PT - 1)) * 256 + threadIdx.x;   // point id
  int bv  = g >> 16;
  int pix = g & (NPIX - 1);
  unsigned long long key = zwin[g];
  bool hit = (key != ~0ULL);
  int n = (int)(key & 0xffffffffULL);

  if (grp < 4) {                       // 16 feat channels
    int c0 = grp * 16;
    const float* fb = feats + (size_t)bv * CF * NPIX + (size_t)c0 * NPIX;
    float* o0 = out0 + (size_t)bv * CF * NPIX + (size_t)c0 * NPIX + pix;
    if (hit) {
      #pragma unroll
      for (int c = 0; c < 16; ++c)
        __builtin_nontemporal_store(fb[(size_t)c * NPIX + n], &o0[(size_t)c * NPIX]);
    } else {
      #pragma unroll
      for (int c = 0; c < 16; ++c)
        __builtin_nontemporal_store(0.0f, &o0[(size_t)c * NPIX]);
    }
  } else {                             // colors (V,B,3,H,W layout!) + depth
    int b = bv >> 1, v = bv & 1;       // V_ == 2
    const float* cb = colr + (size_t)bv * 3 * NPIX;
    float* o1 = out1 + (size_t)(v * B_ + b) * 3 * NPIX + pix;
    if (hit) {
      float z = __uint_as_float((unsigned)(key >> 32));
      __builtin_nontemporal_store((z < BIGF) ? z : 0.0f, &out2[g]);
      #pragma unroll
      for (int ch = 0; ch < 3; ++ch)
        __builtin_nontemporal_store(cb[(size_t)ch * NPIX + n] * 0.5f + 0.5f,
                                    &o1[(size_t)ch * NPIX]);
    } else {
      __builtin_nontemporal_store(0.0f, &out2[g]);
      #pragma unroll
      for (int ch = 0; ch < 3; ++ch)
        __builtin_nontemporal_store(0.0f, &o1[(size_t)ch * NPIX]);
    }
  }
}

extern "C" void kernel_launch(void* const* d_in, const int* in_sizes, int n_in,
                              void* d_out, int out_size, void* d_ws, size_t ws_size,
                              hipStream_t stream) {
  const float* depths     = (const float*)d_in[0];
  const float* colors     = (const float*)d_in[1];
  const float* feats      = (const float*)d_in[2];
  const float* K          = (const float*)d_in[3];
  const float* src_RTinvs = (const float*)d_in[5];
  const float* dst_RTs    = (const float*)d_in[6];

  float* out0 = (float*)d_out;                                  // (B,V,64,256,256)
  float* out1 = out0 + (size_t)B_ * V_ * CF * NPIX;             // (V,B,3,256,256)
  float* out2 = out1 + (size_t)V_ * B_ * 3 * NPIX;              // (B,V,1,256,256)

  unsigned long long* zwin = (unsigned long long*)d_ws;         // 2 MiB
  float* colr = (float*)(zwin + NPT);                           // 3 MiB
  float* mats = colr + (size_t)B_ * V_ * 3 * NPIX;              // 256 B
  float* tf   = (float*)((char*)d_ws + WS_BASE);                // 64 MiB (16B-aligned)

  const bool use_tf = (ws_size >= WS_BASE + TF_BYTES);

  int prep_grid = use_tf ? (TRANSP_BLKS + RESIZE_BLKS) : RESIZE_BLKS;
  prep_k<<<prep_grid, 256, 0, stream>>>(K, colors, feats, colr, mats, zwin, tf);
  splat_k<<<NBLK_PT, 256, 0, stream>>>(depths, mats, src_RTinvs, dst_RTs, zwin);
  if (use_tf)
    gatherT_k<<<5 * NBLK_PT, 256, 0, stream>>>(zwin, tf, colr, out0, out1, out2);
  else
    gather_k<<<5 * NBLK_PT, 256, 0, stream>>>(zwin, feats, colr, out0, out1, out2);
}